// Round 1
// baseline (55.887 us; speedup 1.0000x reference)
//
#include <hip/hip_runtime.h>

#define CROP 7
#define CH 256
#define IMH 200
#define IMW 304

__global__ __launch_bounds__(256) void roialign_kernel(
    const float* __restrict__ fm, const float* __restrict__ boxes,
    const int* __restrict__ box_ind, float* __restrict__ out, int total)
{
    int idx = blockIdx.x * blockDim.x + threadIdx.x;
    if (idx >= total) return;

    int ix = idx % CROP;
    int t  = idx / CROP;
    int iy = t % CROP;
    t /= CROP;
    int c = t % CH;
    int m = t / CH;

    // box params (wave-uniform in m -> scalar loads)
    float x1 = boxes[4 * m + 0];
    float y1 = boxes[4 * m + 1];
    float x2 = boxes[4 * m + 2];
    float y2 = boxes[4 * m + 3];

    const float Wm1 = (float)(IMW - 1);
    const float Hm1 = (float)(IMH - 1);

    // replicate reference(): normalize
    float spacing_w = (x2 - x1) / (float)CROP;
    float spacing_h = (y2 - y1) / (float)CROP;
    float nx0 = (x1 + spacing_w * 0.5f - 0.5f) / Wm1;
    float ny0 = (y1 + spacing_h * 0.5f - 0.5f) / Hm1;
    float nw = spacing_w * (float)(CROP - 1) / Wm1;
    float nh = spacing_h * (float)(CROP - 1) / Hm1;

    // replicate _crop_and_resize(): denormalize
    float y1n = ny0, x1n = nx0;
    float y2n = ny0 + nh, x2n = nx0 + nw;
    float h_scale = (y2n - y1n) * Hm1 / (float)(CROP - 1);
    float w_scale = (x2n - x1n) * Wm1 / (float)(CROP - 1);
    float in_y = y1n * Hm1 + (float)iy * h_scale;
    float in_x = x1n * Wm1 + (float)ix * w_scale;

    bool valid = (in_y >= 0.0f) && (in_y <= Hm1) && (in_x >= 0.0f) && (in_x <= Wm1);

    float top   = floorf(in_y);
    float bot   = ceilf(in_y);
    float left  = floorf(in_x);
    float right = ceilf(in_x);
    float ly = in_y - top;
    float lx = in_x - left;

    int ti = (int)fminf(fmaxf(top,   0.0f), Hm1);
    int bi = (int)fminf(fmaxf(bot,   0.0f), Hm1);
    int li = (int)fminf(fmaxf(left,  0.0f), Wm1);
    int ri = (int)fminf(fmaxf(right, 0.0f), Wm1);

    int b = box_ind[m];
    const float* __restrict__ plane = fm + ((size_t)b * CH + c) * (size_t)(IMH * IMW);

    float tl = plane[ti * IMW + li];
    float tr = plane[ti * IMW + ri];
    float bl = plane[bi * IMW + li];
    float br = plane[bi * IMW + ri];

    float topv = tl + (tr - tl) * lx;
    float botv = bl + (br - bl) * lx;
    float val  = topv + (botv - topv) * ly;

    out[idx] = valid ? val : 0.0f;
}

extern "C" void kernel_launch(void* const* d_in, const int* in_sizes, int n_in,
                              void* d_out, int out_size, void* d_ws, size_t ws_size,
                              hipStream_t stream) {
    const float* fm      = (const float*)d_in[0];
    const float* boxes   = (const float*)d_in[1];
    const int*   box_ind = (const int*)d_in[2];
    float*       out     = (float*)d_out;

    int total = out_size;  // 512*256*7*7
    int block = 256;
    int grid = (total + block - 1) / block;
    roialign_kernel<<<grid, block, 0, stream>>>(fm, boxes, box_ind, out, total);
}

// Round 2
// 34.969 us; speedup vs baseline: 1.5982x; 1.5982x over previous
//
#include <hip/hip_runtime.h>

#define CROP 7
#define CH 256
#define NBOX 512
#define IMH 200
#define IMW 304
#define NXCD 8

__global__ __launch_bounds__(256) void roialign_kernel(
    const float* __restrict__ fm, const float* __restrict__ boxes,
    const int* __restrict__ box_ind, float* __restrict__ out)
{
    // Chunked XCD swizzle: blocks dispatch round-robin over 8 XCDs;
    // remap so XCD k gets a CONTIGUOUS chunk of the (c-outer) iteration
    // space -> each XCD owns ~32 channels, planes stay L2-resident.
    const int nblocks = (NBOX * CH * CROP * CROP) / 256;  // 25088, %8==0
    const int chunk = nblocks / NXCD;                     // 3136
    int b = blockIdx.x;
    int newb = (b % NXCD) * chunk + b / NXCD;

    // e enumerated c-OUTER, m middle, (iy,ix) inner
    int e = newb * 256 + threadIdx.x;
    int ix = e % CROP;
    int t  = e / CROP;
    int iy = t % CROP;
    t /= CROP;
    int m = t % NBOX;
    int c = t / NBOX;

    // box params
    float x1 = boxes[4 * m + 0];
    float y1 = boxes[4 * m + 1];
    float x2 = boxes[4 * m + 2];
    float y2 = boxes[4 * m + 3];

    const float Wm1 = (float)(IMW - 1);
    const float Hm1 = (float)(IMH - 1);

    // replicate reference(): normalize
    float spacing_w = (x2 - x1) / (float)CROP;
    float spacing_h = (y2 - y1) / (float)CROP;
    float nx0 = (x1 + spacing_w * 0.5f - 0.5f) / Wm1;
    float ny0 = (y1 + spacing_h * 0.5f - 0.5f) / Hm1;
    float nw = spacing_w * (float)(CROP - 1) / Wm1;
    float nh = spacing_h * (float)(CROP - 1) / Hm1;

    // replicate _crop_and_resize(): denormalize
    float h_scale = nh * Hm1 / (float)(CROP - 1);
    float w_scale = nw * Wm1 / (float)(CROP - 1);
    float in_y = ny0 * Hm1 + (float)iy * h_scale;
    float in_x = nx0 * Wm1 + (float)ix * w_scale;

    bool valid = (in_y >= 0.0f) && (in_y <= Hm1) && (in_x >= 0.0f) && (in_x <= Wm1);

    float top   = floorf(in_y);
    float bot   = ceilf(in_y);
    float left  = floorf(in_x);
    float right = ceilf(in_x);
    float ly = in_y - top;
    float lx = in_x - left;

    int ti = (int)fminf(fmaxf(top,   0.0f), Hm1);
    int bi = (int)fminf(fmaxf(bot,   0.0f), Hm1);
    int li = (int)fminf(fmaxf(left,  0.0f), Wm1);
    int ri = (int)fminf(fmaxf(right, 0.0f), Wm1);

    int bimg = box_ind[m];
    const float* __restrict__ plane = fm + ((size_t)bimg * CH + c) * (size_t)(IMH * IMW);

    float tl = plane[ti * IMW + li];
    float tr = plane[ti * IMW + ri];
    float bl = plane[bi * IMW + li];
    float br = plane[bi * IMW + ri];

    float topv = tl + (tr - tl) * lx;
    float botv = bl + (br - bl) * lx;
    float val  = topv + (botv - topv) * ly;

    // out layout: [m][c][iy][ix]
    int oidx = ((m * CH + c) * CROP + iy) * CROP + ix;
    out[oidx] = valid ? val : 0.0f;
}

extern "C" void kernel_launch(void* const* d_in, const int* in_sizes, int n_in,
                              void* d_out, int out_size, void* d_ws, size_t ws_size,
                              hipStream_t stream) {
    const float* fm      = (const float*)d_in[0];
    const float* boxes   = (const float*)d_in[1];
    const int*   box_ind = (const int*)d_in[2];
    float*       out     = (float*)d_out;

    int total = NBOX * CH * CROP * CROP;  // 6,422,528 == out_size
    int block = 256;
    int grid = total / block;             // 25088 exactly
    roialign_kernel<<<grid, block, 0, stream>>>(fm, boxes, box_ind, out);
}

// Round 3
// 31.908 us; speedup vs baseline: 1.7515x; 1.0959x over previous
//
#include <hip/hip_runtime.h>

#define CROP 7
#define CH 256
#define NBOX 512
#define IMH 200
#define IMW 304
#define PLANE (IMH * IMW)   // 60800
#define NXCD 8
#define CPT 4               // channels per thread

__global__ __launch_bounds__(256) void roialign_kernel(
    const float* __restrict__ fm, const float* __restrict__ boxes,
    const int* __restrict__ box_ind, float* __restrict__ out)
{
    // total threads = NBOX * 49 * (CH/CPT) = 512*49*64 = 1,605,632 = 6272 blocks
    const int nblocks = (NBOX * 49 * (CH / CPT)) / 256;   // 6272, %8==0
    const int chunk = nblocks / NXCD;                      // 784
    int b = blockIdx.x;
    int newb = (b % NXCD) * chunk + b / NXCD;  // XCD k owns contiguous cblk range

    // e enumerated: cblk OUTER, m middle, s=(iy,ix) inner
    int e = newb * 256 + threadIdx.x;
    int s = e % 49;
    int t = e / 49;
    int m = t % NBOX;
    int cblk = t / NBOX;          // 0..63
    int c0 = cblk * CPT;
    int ix = s % CROP;
    int iy = s / CROP;

    float x1 = boxes[4 * m + 0];
    float y1 = boxes[4 * m + 1];
    float x2 = boxes[4 * m + 2];
    float y2 = boxes[4 * m + 3];

    const float Wm1 = (float)(IMW - 1);
    const float Hm1 = (float)(IMH - 1);

    // replicate reference(): normalize
    float spacing_w = (x2 - x1) / (float)CROP;
    float spacing_h = (y2 - y1) / (float)CROP;
    float nx0 = (x1 + spacing_w * 0.5f - 0.5f) / Wm1;
    float ny0 = (y1 + spacing_h * 0.5f - 0.5f) / Hm1;
    float nw = spacing_w * (float)(CROP - 1) / Wm1;
    float nh = spacing_h * (float)(CROP - 1) / Hm1;

    // replicate _crop_and_resize(): denormalize
    float h_scale = nh * Hm1 / (float)(CROP - 1);
    float w_scale = nw * Wm1 / (float)(CROP - 1);
    float in_y = ny0 * Hm1 + (float)iy * h_scale;
    float in_x = nx0 * Wm1 + (float)ix * w_scale;

    bool valid = (in_y >= 0.0f) && (in_y <= Hm1) && (in_x >= 0.0f) && (in_x <= Wm1);

    float top   = floorf(in_y);
    float bot   = ceilf(in_y);
    float left  = floorf(in_x);
    float right = ceilf(in_x);
    float ly = in_y - top;
    float lx = in_x - left;

    int ti = (int)fminf(fmaxf(top,   0.0f), Hm1);
    int bi = (int)fminf(fmaxf(bot,   0.0f), Hm1);
    int li = (int)fminf(fmaxf(left,  0.0f), Wm1);
    int ri = (int)fminf(fmaxf(right, 0.0f), Wm1);

    int off_tl = ti * IMW + li;
    int off_tr = ti * IMW + ri;
    int off_bl = bi * IMW + li;
    int off_br = bi * IMW + ri;

    int bimg = box_ind[m];
    const float* __restrict__ p = fm + ((size_t)bimg * CH + c0) * (size_t)PLANE;

    // 16 independent gathers in flight (4 channels x 4 corners)
    float tl0 = p[off_tl];            float tr0 = p[off_tr];
    float bl0 = p[off_bl];            float br0 = p[off_br];
    float tl1 = p[off_tl + PLANE];    float tr1 = p[off_tr + PLANE];
    float bl1 = p[off_bl + PLANE];    float br1 = p[off_br + PLANE];
    float tl2 = p[off_tl + 2*PLANE];  float tr2 = p[off_tr + 2*PLANE];
    float bl2 = p[off_bl + 2*PLANE];  float br2 = p[off_br + 2*PLANE];
    float tl3 = p[off_tl + 3*PLANE];  float tr3 = p[off_tr + 3*PLANE];
    float bl3 = p[off_bl + 3*PLANE];  float br3 = p[off_br + 3*PLANE];

    float t0 = tl0 + (tr0 - tl0) * lx, b0 = bl0 + (br0 - bl0) * lx;
    float t1 = tl1 + (tr1 - tl1) * lx, b1 = bl1 + (br1 - bl1) * lx;
    float t2 = tl2 + (tr2 - tl2) * lx, b2 = bl2 + (br2 - bl2) * lx;
    float t3 = tl3 + (tr3 - tl3) * lx, b3 = bl3 + (br3 - bl3) * lx;
    float v0 = t0 + (b0 - t0) * ly;
    float v1 = t1 + (b1 - t1) * ly;
    float v2 = t2 + (b2 - t2) * ly;
    float v3 = t3 + (b3 - t3) * ly;
    if (!valid) { v0 = 0.0f; v1 = 0.0f; v2 = 0.0f; v3 = 0.0f; }

    // out layout: [m][c][iy][ix]; channel stride = 49 floats
    int obase = (m * CH + c0) * 49 + s;
    __builtin_nontemporal_store(v0, &out[obase]);
    __builtin_nontemporal_store(v1, &out[obase + 49]);
    __builtin_nontemporal_store(v2, &out[obase + 2*49]);
    __builtin_nontemporal_store(v3, &out[obase + 3*49]);
}

extern "C" void kernel_launch(void* const* d_in, const int* in_sizes, int n_in,
                              void* d_out, int out_size, void* d_ws, size_t ws_size,
                              hipStream_t stream) {
    const float* fm      = (const float*)d_in[0];
    const float* boxes   = (const float*)d_in[1];
    const int*   box_ind = (const int*)d_in[2];
    float*       out     = (float*)d_out;

    int grid = (NBOX * 49 * (CH / CPT)) / 256;  // 6272
    roialign_kernel<<<grid, 256, 0, stream>>>(fm, boxes, box_ind, out);
}

// Round 4
// 28.082 us; speedup vs baseline: 1.9901x; 1.1362x over previous
//
#include <hip/hip_runtime.h>

#define CROP 7
#define CH 256
#define NBOX 512
#define IMH 200
#define IMW 304
#define PLANE (IMH * IMW)   // 60800
#define NXCD 8
#define CPT 4               // channels per thread

__device__ __forceinline__ float2 ld2(const float* __restrict__ p) {
    float2 v;
    __builtin_memcpy(&v, p, sizeof(float2));  // 4B-aligned; gfx950 unaligned dwordx2 OK
    return v;
}

__global__ __launch_bounds__(256) void roialign_kernel(
    const float* __restrict__ fm, const float* __restrict__ boxes,
    const int* __restrict__ box_ind, float* __restrict__ out)
{
    // total threads = NBOX * 49 * (CH/CPT) = 512*49*64 -> 6272 blocks
    const int nblocks = (NBOX * 49 * (CH / CPT)) / 256;   // 6272, %8==0
    const int chunk = nblocks / NXCD;                      // 784
    int b = blockIdx.x;
    int newb = (b % NXCD) * chunk + b / NXCD;  // XCD k owns contiguous cblk range

    // e enumerated: cblk OUTER, m middle, s=(iy,ix) inner
    int e = newb * 256 + threadIdx.x;
    int s = e % 49;
    int t = e / 49;
    int m = t % NBOX;
    int cblk = t / NBOX;          // 0..63
    int c0 = cblk * CPT;
    int ix = s % CROP;
    int iy = s / CROP;

    float x1 = boxes[4 * m + 0];
    float y1 = boxes[4 * m + 1];
    float x2 = boxes[4 * m + 2];
    float y2 = boxes[4 * m + 3];

    const float Wm1 = (float)(IMW - 1);
    const float Hm1 = (float)(IMH - 1);

    // replicate reference(): normalize
    float spacing_w = (x2 - x1) / (float)CROP;
    float spacing_h = (y2 - y1) / (float)CROP;
    float nx0 = (x1 + spacing_w * 0.5f - 0.5f) / Wm1;
    float ny0 = (y1 + spacing_h * 0.5f - 0.5f) / Hm1;
    float nw = spacing_w * (float)(CROP - 1) / Wm1;
    float nh = spacing_h * (float)(CROP - 1) / Hm1;

    // replicate _crop_and_resize(): denormalize
    float h_scale = nh * Hm1 / (float)(CROP - 1);
    float w_scale = nw * Wm1 / (float)(CROP - 1);
    float in_y = ny0 * Hm1 + (float)iy * h_scale;
    float in_x = nx0 * Wm1 + (float)ix * w_scale;

    bool valid = (in_y >= 0.0f) && (in_y <= Hm1) && (in_x >= 0.0f) && (in_x <= Wm1);

    float top   = floorf(in_y);
    float left  = floorf(in_x);
    float bot   = ceilf(in_y);
    float ly = in_y - top;
    float lx = in_x - left;

    int ti = (int)fminf(fmaxf(top,  0.0f), Hm1);
    int bi = (int)fminf(fmaxf(bot,  0.0f), Hm1);
    int li = (int)fminf(fmaxf(left, 0.0f), Wm1);

    int cb = li < (IMW - 2) ? li : (IMW - 2);   // merged-load base column
    bool sel = (li > cb);                        // li == W-1 -> take .y

    int off_t = ti * IMW + cb;
    int off_b = bi * IMW + cb;

    int bimg = box_ind[m];
    const float* __restrict__ p = fm + ((size_t)bimg * CH + c0) * (size_t)PLANE;

    // 8 independent 8B gathers (4 channels x {top,bottom} row pairs)
    float2 t0 = ld2(p + off_t);             float2 b0 = ld2(p + off_b);
    float2 t1 = ld2(p + off_t + PLANE);     float2 b1 = ld2(p + off_b + PLANE);
    float2 t2 = ld2(p + off_t + 2*PLANE);   float2 b2 = ld2(p + off_b + 2*PLANE);
    float2 t3 = ld2(p + off_t + 3*PLANE);   float2 b3 = ld2(p + off_b + 3*PLANE);

    // tl = sel ? .y : .x ; tr = .y (whenever .y is not the true tr, lx==0 or invalid)
    float tl0 = sel ? t0.y : t0.x, bl0 = sel ? b0.y : b0.x;
    float tl1 = sel ? t1.y : t1.x, bl1 = sel ? b1.y : b1.x;
    float tl2 = sel ? t2.y : t2.x, bl2 = sel ? b2.y : b2.x;
    float tl3 = sel ? t3.y : t3.x, bl3 = sel ? b3.y : b3.x;

    float tv0 = tl0 + (t0.y - tl0) * lx, bv0 = bl0 + (b0.y - bl0) * lx;
    float tv1 = tl1 + (t1.y - tl1) * lx, bv1 = bl1 + (b1.y - bl1) * lx;
    float tv2 = tl2 + (t2.y - tl2) * lx, bv2 = bl2 + (b2.y - bl2) * lx;
    float tv3 = tl3 + (t3.y - tl3) * lx, bv3 = bl3 + (b3.y - bl3) * lx;

    float v0 = tv0 + (bv0 - tv0) * ly;
    float v1 = tv1 + (bv1 - tv1) * ly;
    float v2 = tv2 + (bv2 - tv2) * ly;
    float v3 = tv3 + (bv3 - tv3) * ly;
    if (!valid) { v0 = 0.0f; v1 = 0.0f; v2 = 0.0f; v3 = 0.0f; }

    // out layout: [m][c][iy][ix]; channel stride = 49 floats
    int obase = (m * CH + c0) * 49 + s;
    __builtin_nontemporal_store(v0, &out[obase]);
    __builtin_nontemporal_store(v1, &out[obase + 49]);
    __builtin_nontemporal_store(v2, &out[obase + 2*49]);
    __builtin_nontemporal_store(v3, &out[obase + 3*49]);
}

extern "C" void kernel_launch(void* const* d_in, const int* in_sizes, int n_in,
                              void* d_out, int out_size, void* d_ws, size_t ws_size,
                              hipStream_t stream) {
    const float* fm      = (const float*)d_in[0];
    const float* boxes   = (const float*)d_in[1];
    const int*   box_ind = (const int*)d_in[2];
    float*       out     = (float*)d_out;

    int grid = (NBOX * 49 * (CH / CPT)) / 256;  // 6272
    roialign_kernel<<<grid, 256, 0, stream>>>(fm, boxes, box_ind, out);
}